// Round 5
// baseline (297.822 us; speedup 1.0000x reference)
//
#include <hip/hip_runtime.h>
#include <hip/hip_fp16.h>

// out[M,N] = fp16( a[M,K] @ (w_q[K,N] * scale[K/G,N]) ), G=128, all dims 4096.
// Harness dtype contract: fp16 tensors passed/returned as FLOAT32.
// Round 5: trickle-issue LDS reads (queue-backpressure theory). Round-4's
// up-front 12-read burst fills the LDS queue: the wave stalls at read-issue,
// so LDS and MFMA pipes serialize (phase = 1152+1242 cyc, = measured 53%
// MfmaUtil). Now: phase top issues 8 reads (bf0-3, af0-3) + stage; each
// 8-MFMA cluster then issues the next 2 af reads; lgkmcnt(2) waits pair with
// the 2 in-flight reads. Reads trickle into the queue between MFMA clusters
// (m201/HK pattern). Also: bijective XCD swizzle of block id (256 = 8*32).
#define MDIM 4096
#define NDIM 4096
#define KDIM 4096
#define NT 256
#define WBLK 4096

typedef _Float16 f16x8 __attribute__((ext_vector_type(8)));
typedef float f32x4 __attribute__((ext_vector_type(4)));
typedef unsigned int u32;
typedef unsigned short u16;

__device__ inline __half2 as_half2(u32 u) { return __builtin_bit_cast(__half2, u); }
__device__ inline u32 as_u32(__half2 h) { return __builtin_bit_cast(u32, h); }
// __builtin_amdgcn_cvt_pkrtz returns __fp16 ext_vector(2); bit-cast directly.
__device__ inline u32 pkrtz(float a, float b) {
  return __builtin_bit_cast(u32, __builtin_amdgcn_cvt_pkrtz(a, b));
}

// async global -> LDS, 16 B/lane. LDS dst must be wave-uniform base + lane*16.
__device__ inline void load16_to_lds(const void* g, void* l) {
  __builtin_amdgcn_global_load_lds(
      (__attribute__((address_space(1))) const u32*)g,
      (__attribute__((address_space(3))) u32*)l,
      16, 0, 0);
}

template <int VM>
__device__ __forceinline__ void wait_vmcnt() {
  if constexpr (VM == 8)
    asm volatile("s_waitcnt vmcnt(8)" ::: "memory");
  else if constexpr (VM == 4)
    asm volatile("s_waitcnt vmcnt(4)" ::: "memory");
  else
    asm volatile("s_waitcnt vmcnt(0)" ::: "memory");
}

template <int LK>
__device__ __forceinline__ void wait_lgkm() {
  if constexpr (LK == 2)
    asm volatile("s_waitcnt lgkmcnt(2)" ::: "memory");
  else
    asm volatile("s_waitcnt lgkmcnt(0)" ::: "memory");
  __builtin_amdgcn_sched_barrier(0);  // keep MFMAs below the wait (rule 18)
}

// ---- fused prepass: blocks [0,4096) dequant+transpose W, rest copy A ----
__global__ __launch_bounds__(NT) void prep(const float* __restrict__ A,
                                           _Float16* __restrict__ A16,
                                           const int* __restrict__ Wq,
                                           const float* __restrict__ Sc,
                                           _Float16* __restrict__ Wt) {
  // u32 staging [n][k-pair], stride 33 dwords: write bank (n+kp)%32 (2-way),
  // read bank (n+k2c+j)%32 (2-way). 8.25 KB -> high occupancy.
  __shared__ u32 Lt[64 * 33];
  const int tid = threadIdx.x;

  if (blockIdx.x >= WBLK) {
    // ---- A fp32 -> fp16 (exact: values are fp16-representable) ----
    const size_t b = blockIdx.x - WBLK;
    const size_t base = (b * NT + tid) * 8;
    const float4 f0 = *(const float4*)(A + base);
    const float4 f1 = *(const float4*)(A + base + 4);
    u32 pk[4];
    pk[0] = pkrtz(f0.x, f0.y);
    pk[1] = pkrtz(f0.z, f0.w);
    pk[2] = pkrtz(f1.x, f1.y);
    pk[3] = pkrtz(f1.z, f1.w);
    *(uint4*)(A16 + base) = *(const uint4*)pk;
    return;
  }

  // ---- W: dequant Wq [K][N] + transpose -> Wt f16 [N][K], 64x64 tile ----
  const int n0 = (blockIdx.x & 63) * 64;
  const int k0 = (blockIdx.x >> 6) * 64;
  const int g = k0 >> 7;  // 64-tile lies within one 128-group

  // phase 1: coalesced read of two adjacent k-rows, dequant to packed k-pair
#pragma unroll
  for (int r = 0; r < 2; ++r) {
    const int idx = r * 256 + tid;
    const int kp = idx >> 4;          // k-pair index 0..31
    const int col4 = (idx & 15) * 4;  // n within tile, 4 at a time
    const int4 va = *(const int4*)(Wq + (size_t)(k0 + 2 * kp) * NDIM + n0 + col4);
    const int4 vb = *(const int4*)(Wq + (size_t)(k0 + 2 * kp + 1) * NDIM + n0 + col4);
    const float4 s = *(const float4*)(Sc + (size_t)g * NDIM + n0 + col4);
    const float sf[4] = {s.x, s.y, s.z, s.w};
    const int av[4] = {va.x, va.y, va.z, va.w};
    const int bv[4] = {vb.x, vb.y, vb.z, vb.w};
#pragma unroll
    for (int i = 0; i < 4; ++i) {
      // fp16 bits of (1024+v): 0x6400|v; hfma gives single-rounded v*s.
      const __half hs = __float2half(sf[i]);
      const __half2 s2 = __half2half2(hs);
      const __half2 nb = __half2half2(__hmul(hs, __float2half(-1024.0f)));
      const u32 u = (u32)av[i] | ((u32)bv[i] << 16) | 0x64006400u;
      // u32 holds (w[2kp]*s, w[2kp+1]*s) = the contiguous k-pair for Wt[n].
      Lt[(size_t)(col4 + i) * 33 + kp] = as_u32(__hfma2(as_half2(u), s2, nb));
    }
  }
  __syncthreads();

  // phase 2: gather 4 k-pair dwords per thread, coalesced 16B writes to Wt
#pragma unroll
  for (int r = 0; r < 2; ++r) {
    const int idx = r * 256 + tid;
    const int n = idx >> 3;          // 0..63
    const int k2c = (idx & 7) * 4;   // dword column 0..28 (= k/2)
    u32 v[4];
#pragma unroll
    for (int j = 0; j < 4; ++j) v[j] = Lt[(size_t)n * 33 + k2c + j];
    *(uint4*)(Wt + (size_t)(n0 + n) * KDIM + k0 + k2c * 2) = *(const uint4*)v;
  }
}

// ---------------- 256x256 counted-vmcnt pipelined f16 GEMM ----------------
// LDS: ring of 4 slots per operand, each slot = one k-half piece
//   [256 rows][4 phys chunks of 16B] (16 KB). Phase p uses slot p&3 and
//   stages the piece for phase p+3 into slot (p+3)&3.
// Swizzle: physical chunk = logical ^ ((row>>1)&3); applied to the per-lane
// GLOBAL source (LDS dst stays linear for global_load_lds) and to frag reads.
// Intra-phase: trickle-issue - 8 reads at top (bf0-3, af0-3), then each
// 8-MFMA cluster issues the next 2 af reads; lgkmcnt(2) pairs with them.
__global__ __launch_bounds__(512, 2) void gemm_f16(const _Float16* __restrict__ A16,
                                                   const _Float16* __restrict__ Wt,
                                                   float* __restrict__ C) {
  __shared__ __align__(16) _Float16 As[4 * 256 * 32];  // 64 KB
  __shared__ __align__(16) _Float16 Bs[4 * 256 * 32];  // 64 KB

  const int tid = threadIdx.x;
  // bijective XCD swizzle: grid 256 = 8 XCDs x 32; XCD x computes tiles
  // [32x, 32x+32) = 2 m-rows x all 16 n -> A-panel reuse within one L2.
  const int swz = (blockIdx.x & 7) * 32 + (blockIdx.x >> 3);
  const int bx = swz & 15;  // n-block
  const int by = swz >> 4;  // m-block
  const int m_base = by * 256;
  const int n_base = bx * 256;

  const int wave = tid >> 6;
  const int lane = tid & 63;
  const int l15 = lane & 15;
  const int quad = lane >> 4;
  const int mq = wave >> 2;  // 0..1 : 128-row band
  const int nq = wave & 3;   // 0..3 : 64-col band
  const int gq = (l15 >> 1) & 3;       // row-swizzle term (row ≡ l15 mod 16)
  const int pchunk = quad ^ gq;        // physical 16B chunk for frag reads

  f32x4 acc[8][4];
#pragma unroll
  for (int i = 0; i < 8; ++i)
#pragma unroll
    for (int j = 0; j < 4; ++j) acc[i][j] = (f32x4)0.0f;

  // stage pieces (A khalf + B khalf) for phase p into slot p&3.
  // 2+2 global_load_lds per thread = 4 vmcnt events per wave per stage.
  auto stage = [&](int p) {
    const int T = p >> 1;        // K-tile
    const int h = p & 1;         // k-half within tile
    const int s = p & 3;         // slot
    const size_t kof = (size_t)T * 64 + (size_t)h * 32;
#pragma unroll
    for (int L = 0; L < 2; ++L) {
      const int cc = L * 512 + tid;        // 0..1023 : (row, phys chunk)
      const int row = cc >> 2;
      const int lch = (cc & 3) ^ ((row >> 1) & 3);  // logical chunk at phys cc&3
      load16_to_lds(A16 + (size_t)(m_base + row) * KDIM + kof + lch * 8,
                    (char*)As + (size_t)s * 16384 + (size_t)cc * 16);
    }
#pragma unroll
    for (int L = 0; L < 2; ++L) {
      const int cc = L * 512 + tid;
      const int row = cc >> 2;
      const int lch = (cc & 3) ^ ((row >> 1) & 3);
      load16_to_lds(Wt + (size_t)(n_base + row) * KDIM + kof + lch * 8,
                    (char*)Bs + (size_t)s * 16384 + (size_t)cc * 16);
    }
  };

  auto phase_body = [&](int p, bool dostage) {
    __builtin_amdgcn_s_barrier();
    asm volatile("" ::: "memory");  // no LDS access hoists above the barrier
    const int s = p & 3;
    const _Float16* Ab = (const _Float16*)((const char*)As + (size_t)s * 16384);
    const _Float16* Bb = (const _Float16*)((const char*)Bs + (size_t)s * 16384);
    f16x8 af[8], bf[4];
    // top batch: bf0..3, af0..3 (8 ds_read_b128) -- keeps queue shallow
#pragma unroll
    for (int j = 0; j < 4; ++j) {
      const int row = nq * 64 + j * 16 + l15;
      bf[j] = *(const f16x8*)(Bb + (size_t)row * 32 + pchunk * 8);
    }
#pragma unroll
    for (int i = 0; i < 4; ++i) {
      const int row = mq * 128 + i * 16 + l15;
      af[i] = *(const f16x8*)(Ab + (size_t)row * 32 + pchunk * 8);
    }
    if (dostage) stage(p + 3);  // VMEM issue overlaps the MFMA clusters

    // cluster 0: rows 0,1 (af2,af3 in flight)
    wait_lgkm<2>();
    __builtin_amdgcn_s_setprio(1);
#pragma unroll
    for (int i = 0; i < 2; ++i)
#pragma unroll
      for (int j = 0; j < 4; ++j)
        acc[i][j] = __builtin_amdgcn_mfma_f32_16x16x32_f16(af[i], bf[j],
                                                           acc[i][j], 0, 0, 0);
    __builtin_amdgcn_s_setprio(0);
    // issue af4,af5 (trickle into LDS queue during cluster 1)
#pragma unroll
    for (int i = 4; i < 6; ++i) {
      const int row = mq * 128 + i * 16 + l15;
      af[i] = *(const f16x8*)(Ab + (size_t)row * 32 + pchunk * 8);
    }
    // cluster 1: rows 2,3 (af4,af5 in flight)
    wait_lgkm<2>();
    __builtin_amdgcn_s_setprio(1);
#pragma unroll
    for (int i = 2; i < 4; ++i)
#pragma unroll
      for (int j = 0; j < 4; ++j)
        acc[i][j] = __builtin_amdgcn_mfma_f32_16x16x32_f16(af[i], bf[j],
                                                           acc[i][j], 0, 0, 0);
    __builtin_amdgcn_s_setprio(0);
    // issue af6,af7
#pragma unroll
    for (int i = 6; i < 8; ++i) {
      const int row = mq * 128 + i * 16 + l15;
      af[i] = *(const f16x8*)(Ab + (size_t)row * 32 + pchunk * 8);
    }
    // cluster 2: rows 4,5 (af6,af7 in flight)
    wait_lgkm<2>();
    __builtin_amdgcn_s_setprio(1);
#pragma unroll
    for (int i = 4; i < 6; ++i)
#pragma unroll
      for (int j = 0; j < 4; ++j)
        acc[i][j] = __builtin_amdgcn_mfma_f32_16x16x32_f16(af[i], bf[j],
                                                           acc[i][j], 0, 0, 0);
    __builtin_amdgcn_s_setprio(0);
    // cluster 3: rows 6,7
    wait_lgkm<0>();
    __builtin_amdgcn_s_setprio(1);
#pragma unroll
    for (int i = 6; i < 8; ++i)
#pragma unroll
      for (int j = 0; j < 4; ++j)
        acc[i][j] = __builtin_amdgcn_mfma_f32_16x16x32_f16(af[i], bf[j],
                                                           acc[i][j], 0, 0, 0);
    __builtin_amdgcn_s_setprio(0);
  };

  // prologue: pieces for phases 0,1,2 (12 vmcnt events in flight)
  stage(0);
  stage(1);
  stage(2);

  // 128 phases = 64 K-tiles x 2 k-halves. vmcnt(8): phases p-1,p-2 in
  // flight, phase p's pieces (staged at p-3) guaranteed landed before the
  // entry barrier (all waves execute the wait pre-barrier).
  for (int p = 0; p < 125; ++p) {
    wait_vmcnt<8>();
    phase_body(p, true);
  }
  wait_vmcnt<8>();
  phase_body(125, false);
  wait_vmcnt<4>();
  phase_body(126, false);
  wait_vmcnt<0>();
  phase_body(127, false);

  // epilogue: C/D layout col=lane&15, row=quad*4+reg; fp16-round, store f32
#pragma unroll
  for (int i = 0; i < 8; ++i) {
#pragma unroll
    for (int j = 0; j < 4; ++j) {
      const int col = n_base + nq * 64 + j * 16 + l15;
#pragma unroll
      for (int r = 0; r < 4; ++r) {
        const int row = m_base + mq * 128 + i * 16 + quad * 4 + r;
        C[(size_t)row * NDIM + col] = __half2float(__float2half(acc[i][j][r]));
      }
    }
  }
}

// ---------------- fallback: fused single-kernel (round-3, 331 us) --------
#define STR 72
__global__ __launch_bounds__(NT) void qgemm_fused(
    const float* __restrict__ A, const int* __restrict__ Wq,
    const float* __restrict__ Sc, float* __restrict__ C) {
  __shared__ __align__(16) _Float16 As[128 * STR];
  __shared__ __align__(16) _Float16 Bs[128 * STR];
  const int tid = threadIdx.x;
  const int bx = blockIdx.x & 31, by = blockIdx.x >> 5;
  const int m_base = by * 128, n_base = bx * 128;
  const int wave = tid >> 6, lane = tid & 63;
  const int l15 = lane & 15, quad = lane >> 4;
  const int wm = (wave & 1) * 64, wn = (wave >> 1) * 64;
  const int bn_local = tid & 127, bk_half = (tid >> 7) * 8;
  const int gn = n_base + bn_local;
  f32x4 acc[4][4];
#pragma unroll
  for (int i = 0; i < 4; ++i)
#pragma unroll
    for (int j = 0; j < 4; ++j) acc[i][j] = (f32x4)0.0f;
  for (int kt = 0; kt < KDIM / 64; ++kt) {
    const int k0 = kt * 64;
    __syncthreads();
#pragma unroll
    for (int i = 0; i < 8; ++i) {
      const int c = i * 256 + tid;
      const int row = c >> 4, col4 = (c & 15) * 4;
      const float4 f = *(const float4*)(A + (size_t)(m_base + row) * KDIM + k0 + col4);
      u32 pk[2];
      pk[0] = pkrtz(f.x, f.y);
      pk[1] = pkrtz(f.z, f.w);
      *(uint2*)&As[(size_t)row * STR + col4] = *(const uint2*)pk;
    }
    {
      const __half hs = __float2half(Sc[(size_t)(k0 >> 7) * NDIM + gn]);
      const __half2 s2 = __half2half2(hs);
      const __half2 nb2 = __half2half2(__hmul(hs, __float2half(-1024.0f)));
#pragma unroll
      for (int it = 0; it < 4; ++it) {
        const int k = bk_half + it * 16;
        u32 v[8];
#pragma unroll
        for (int j = 0; j < 8; ++j)
          v[j] = (u32)Wq[(size_t)(k0 + k + j) * NDIM + gn];
        u32 pk[4];
#pragma unroll
        for (int p = 0; p < 4; ++p) {
          u32 u = v[2 * p] | (v[2 * p + 1] << 16) | 0x64006400u;
          pk[p] = as_u32(__hfma2(as_half2(u), s2, nb2));
        }
        *(uint4*)&Bs[(size_t)bn_local * STR + k] = *(const uint4*)pk;
      }
    }
    __syncthreads();
#pragma unroll
    for (int ks = 0; ks < 64; ks += 32) {
      f16x8 af[4], bf[4];
#pragma unroll
      for (int i = 0; i < 4; ++i)
        af[i] = *(const f16x8*)&As[(size_t)(wm + i * 16 + l15) * STR + ks + quad * 8];
#pragma unroll
      for (int j = 0; j < 4; ++j)
        bf[j] = *(const f16x8*)&Bs[(size_t)(wn + j * 16 + l15) * STR + ks + quad * 8];
#pragma unroll
      for (int i = 0; i < 4; ++i)
#pragma unroll
        for (int j = 0; j < 4; ++j)
          acc[i][j] = __builtin_amdgcn_mfma_f32_16x16x32_f16(af[i], bf[j],
                                                             acc[i][j], 0, 0, 0);
    }
  }
#pragma unroll
  for (int i = 0; i < 4; ++i)
#pragma unroll
    for (int j = 0; j < 4; ++j) {
      const int col = n_base + wn + j * 16 + l15;
#pragma unroll
      for (int r = 0; r < 4; ++r) {
        const int row = m_base + wm + i * 16 + quad * 4 + r;
        C[(size_t)row * NDIM + col] = __half2float(__float2half(acc[i][j][r]));
      }
    }
}

extern "C" void kernel_launch(void* const* d_in, const int* in_sizes, int n_in,
                              void* d_out, int out_size, void* d_ws, size_t ws_size,
                              hipStream_t stream) {
  const float* a = (const float*)d_in[0];
  const int* wq = (const int*)d_in[1];
  const float* sc = (const float*)d_in[2];
  float* out = (float*)d_out;

  const size_t a16_bytes = (size_t)MDIM * KDIM * 2;  // 32 MiB
  const size_t wt_bytes = (size_t)NDIM * KDIM * 2;   // 32 MiB

  if (ws_size >= a16_bytes + wt_bytes) {
    _Float16* a16 = (_Float16*)d_ws;
    _Float16* wt = (_Float16*)((char*)d_ws + a16_bytes);
    const int a_blocks = (MDIM * KDIM) / (NT * 8);  // 8192
    prep<<<WBLK + a_blocks, NT, 0, stream>>>(a, a16, wq, sc, wt);
    gemm_f16<<<(MDIM / 256) * (NDIM / 256), 512, 0, stream>>>(a16, wt, out);
  } else {
    qgemm_fused<<<(MDIM / 128) * (NDIM / 128), NT, 0, stream>>>(a, wq, sc, out);
  }
}

// Round 6
// 291.491 us; speedup vs baseline: 1.0217x; 1.0217x over previous
//
#include <hip/hip_runtime.h>
#include <hip/hip_fp16.h>

// out[M,N] = fp16( a[M,K] @ (w_q[K,N] * scale[K/G,N]) ), G=128, all dims 4096.
// Harness dtype contract: fp16 tensors passed/returned as FLOAT32.
// Round 6: m201-faithful sub-phase schedule (reverts round-5's trickle +
// XCD swizzle, both regressions). Each 32-MFMA piece splits into two
// 16-MFMA sub-phases with reads issued BEFORE the entry barrier (they drain
// during the barrier wait), 2 barriers per sub-phase, 8/4 read split with
// bf-fragment reuse, one operand-piece staged per sub-phase, vmcnt(8) once
// per piece at exit. This is the verified 1563-TF structure's phase shape.
#define MDIM 4096
#define NDIM 4096
#define KDIM 4096
#define NT 256
#define WBLK 4096

typedef _Float16 f16x8 __attribute__((ext_vector_type(8)));
typedef float f32x4 __attribute__((ext_vector_type(4)));
typedef unsigned int u32;
typedef unsigned short u16;

__device__ inline __half2 as_half2(u32 u) { return __builtin_bit_cast(__half2, u); }
__device__ inline u32 as_u32(__half2 h) { return __builtin_bit_cast(u32, h); }
// __builtin_amdgcn_cvt_pkrtz returns __fp16 ext_vector(2); bit-cast directly.
__device__ inline u32 pkrtz(float a, float b) {
  return __builtin_bit_cast(u32, __builtin_amdgcn_cvt_pkrtz(a, b));
}

// async global -> LDS, 16 B/lane. LDS dst must be wave-uniform base + lane*16.
__device__ inline void load16_to_lds(const void* g, void* l) {
  __builtin_amdgcn_global_load_lds(
      (__attribute__((address_space(1))) const u32*)g,
      (__attribute__((address_space(3))) u32*)l,
      16, 0, 0);
}

template <int VM>
__device__ __forceinline__ void wait_vmcnt() {
  if constexpr (VM == 8)
    asm volatile("s_waitcnt vmcnt(8)" ::: "memory");
  else if constexpr (VM == 4)
    asm volatile("s_waitcnt vmcnt(4)" ::: "memory");
  else
    asm volatile("s_waitcnt vmcnt(0)" ::: "memory");
}

__device__ __forceinline__ void wait_lgkm0_fence() {
  asm volatile("s_waitcnt lgkmcnt(0)" ::: "memory");
  __builtin_amdgcn_sched_barrier(0);  // keep MFMAs below the wait (rule 18)
}

__device__ __forceinline__ void barrier_fence() {
  __builtin_amdgcn_s_barrier();
  asm volatile("" ::: "memory");  // no LDS access moves across the barrier
}

// ---- fused prepass: blocks [0,4096) dequant+transpose W, rest copy A ----
__global__ __launch_bounds__(NT) void prep(const float* __restrict__ A,
                                           _Float16* __restrict__ A16,
                                           const int* __restrict__ Wq,
                                           const float* __restrict__ Sc,
                                           _Float16* __restrict__ Wt) {
  // u32 staging [n][k-pair], stride 33 dwords: write bank (n+kp)%32 (2-way),
  // read bank (n+k2c+j)%32 (2-way). 8.25 KB -> high occupancy.
  __shared__ u32 Lt[64 * 33];
  const int tid = threadIdx.x;

  if (blockIdx.x >= WBLK) {
    // ---- A fp32 -> fp16 (exact: values are fp16-representable) ----
    const size_t b = blockIdx.x - WBLK;
    const size_t base = (b * NT + tid) * 8;
    const float4 f0 = *(const float4*)(A + base);
    const float4 f1 = *(const float4*)(A + base + 4);
    u32 pk[4];
    pk[0] = pkrtz(f0.x, f0.y);
    pk[1] = pkrtz(f0.z, f0.w);
    pk[2] = pkrtz(f1.x, f1.y);
    pk[3] = pkrtz(f1.z, f1.w);
    *(uint4*)(A16 + base) = *(const uint4*)pk;
    return;
  }

  // ---- W: dequant Wq [K][N] + transpose -> Wt f16 [N][K], 64x64 tile ----
  const int n0 = (blockIdx.x & 63) * 64;
  const int k0 = (blockIdx.x >> 6) * 64;
  const int g = k0 >> 7;  // 64-tile lies within one 128-group

  // phase 1: coalesced read of two adjacent k-rows, dequant to packed k-pair
#pragma unroll
  for (int r = 0; r < 2; ++r) {
    const int idx = r * 256 + tid;
    const int kp = idx >> 4;          // k-pair index 0..31
    const int col4 = (idx & 15) * 4;  // n within tile, 4 at a time
    const int4 va = *(const int4*)(Wq + (size_t)(k0 + 2 * kp) * NDIM + n0 + col4);
    const int4 vb = *(const int4*)(Wq + (size_t)(k0 + 2 * kp + 1) * NDIM + n0 + col4);
    const float4 s = *(const float4*)(Sc + (size_t)g * NDIM + n0 + col4);
    const float sf[4] = {s.x, s.y, s.z, s.w};
    const int av[4] = {va.x, va.y, va.z, va.w};
    const int bv[4] = {vb.x, vb.y, vb.z, vb.w};
#pragma unroll
    for (int i = 0; i < 4; ++i) {
      // fp16 bits of (1024+v): 0x6400|v; hfma gives single-rounded v*s.
      const __half hs = __float2half(sf[i]);
      const __half2 s2 = __half2half2(hs);
      const __half2 nb = __half2half2(__hmul(hs, __float2half(-1024.0f)));
      const u32 u = (u32)av[i] | ((u32)bv[i] << 16) | 0x64006400u;
      // u32 holds (w[2kp]*s, w[2kp+1]*s) = the contiguous k-pair for Wt[n].
      Lt[(size_t)(col4 + i) * 33 + kp] = as_u32(__hfma2(as_half2(u), s2, nb));
    }
  }
  __syncthreads();

  // phase 2: gather 4 k-pair dwords per thread, coalesced 16B writes to Wt
#pragma unroll
  for (int r = 0; r < 2; ++r) {
    const int idx = r * 256 + tid;
    const int n = idx >> 3;          // 0..63
    const int k2c = (idx & 7) * 4;   // dword column 0..28 (= k/2)
    u32 v[4];
#pragma unroll
    for (int j = 0; j < 4; ++j) v[j] = Lt[(size_t)n * 33 + k2c + j];
    *(uint4*)(Wt + (size_t)(n0 + n) * KDIM + k0 + k2c * 2) = *(const uint4*)v;
  }
}

// ---------------- 256x256 counted-vmcnt pipelined f16 GEMM ----------------
// LDS: ring of 4 slots per operand, each slot = one k-half piece
//   [256 rows][4 phys chunks of 16B] (16 KB). Piece p uses slot p&3 and
//   stages piece p+3 into slot (p+3)&3 (its last readers drained before any
//   wave entered piece p).
// Swizzle: physical chunk = logical ^ ((row>>1)&3); applied to the per-lane
// GLOBAL source (LDS dst stays linear for global_load_lds) and to frag reads.
// Piece = 2 sub-phases (m201 template):
//   sub-a: read af0-3,bf0-3 (8xb128); stageA(p+3); BAR; lgkm0; 16 MFMA; BAR
//   sub-b: read af4-7 (4xb128);       stageB(p+3); BAR; lgkm0; 16 MFMA
//   [vmcnt(8)] BAR   <- once per piece, guarantees piece p+1 landed
// Reads sit BEFORE the barrier so they drain during barrier wait / other
// waves' MFMA tail; bf frags are reused across sub-phases.
__global__ __launch_bounds__(512, 2) void gemm_f16(const _Float16* __restrict__ A16,
                                                   const _Float16* __restrict__ Wt,
                                                   float* __restrict__ C) {
  __shared__ __align__(16) _Float16 As[4 * 256 * 32];  // 64 KB
  __shared__ __align__(16) _Float16 Bs[4 * 256 * 32];  // 64 KB

  const int tid = threadIdx.x;
  const int bx = blockIdx.x & 15;  // n-block
  const int by = blockIdx.x >> 4;  // m-block
  const int m_base = by * 256;
  const int n_base = bx * 256;

  const int wave = tid >> 6;
  const int lane = tid & 63;
  const int l15 = lane & 15;
  const int quad = lane >> 4;
  const int mq = wave >> 2;  // 0..1 : 128-row band
  const int nq = wave & 3;   // 0..3 : 64-col band
  const int gq = (l15 >> 1) & 3;       // row-swizzle term (row ≡ l15 mod 16)
  const int pchunk = quad ^ gq;        // physical 16B chunk for frag reads

  f32x4 acc[8][4];
#pragma unroll
  for (int i = 0; i < 8; ++i)
#pragma unroll
    for (int j = 0; j < 4; ++j) acc[i][j] = (f32x4)0.0f;

  // stage A (or B) k-half piece q into slot q&3: 2 global_load_lds / thread.
  auto stageA = [&](int q) {
    const size_t kof = (size_t)q * 32;
    const int s = q & 3;
#pragma unroll
    for (int L = 0; L < 2; ++L) {
      const int cc = L * 512 + tid;        // 0..1023 : (row, phys chunk)
      const int row = cc >> 2;
      const int lch = (cc & 3) ^ ((row >> 1) & 3);  // logical chunk at phys cc&3
      load16_to_lds(A16 + (size_t)(m_base + row) * KDIM + kof + lch * 8,
                    (char*)As + (size_t)s * 16384 + (size_t)cc * 16);
    }
  };
  auto stageB = [&](int q) {
    const size_t kof = (size_t)q * 32;
    const int s = q & 3;
#pragma unroll
    for (int L = 0; L < 2; ++L) {
      const int cc = L * 512 + tid;
      const int row = cc >> 2;
      const int lch = (cc & 3) ^ ((row >> 1) & 3);
      load16_to_lds(Wt + (size_t)(n_base + row) * KDIM + kof + lch * 8,
                    (char*)Bs + (size_t)s * 16384 + (size_t)cc * 16);
    }
  };

  auto piece = [&](int p, bool dostage) {
    const int s = p & 3;
    const _Float16* Ab = (const _Float16*)((const char*)As + (size_t)s * 16384);
    const _Float16* Bb = (const _Float16*)((const char*)Bs + (size_t)s * 16384);
    f16x8 af[8], bf[4];

    // ---------- sub-phase a: quadrant qm=0 ----------
#pragma unroll
    for (int i = 0; i < 4; ++i) {
      const int row = mq * 128 + i * 16 + l15;
      af[i] = *(const f16x8*)(Ab + (size_t)row * 32 + pchunk * 8);
    }
#pragma unroll
    for (int j = 0; j < 4; ++j) {
      const int row = nq * 64 + j * 16 + l15;
      bf[j] = *(const f16x8*)(Bb + (size_t)row * 32 + pchunk * 8);
    }
    if (dostage) stageA(p + 3);
    barrier_fence();
    wait_lgkm0_fence();
    __builtin_amdgcn_s_setprio(1);
#pragma unroll
    for (int i = 0; i < 4; ++i)
#pragma unroll
      for (int j = 0; j < 4; ++j)
        acc[i][j] = __builtin_amdgcn_mfma_f32_16x16x32_f16(af[i], bf[j],
                                                           acc[i][j], 0, 0, 0);
    __builtin_amdgcn_s_setprio(0);
    barrier_fence();

    // ---------- sub-phase b: quadrant qm=1 (bf reuse) ----------
#pragma unroll
    for (int i = 4; i < 8; ++i) {
      const int row = mq * 128 + i * 16 + l15;
      af[i] = *(const f16x8*)(Ab + (size_t)row * 32 + pchunk * 8);
    }
    if (dostage) stageB(p + 3);
    barrier_fence();
    wait_lgkm0_fence();
    __builtin_amdgcn_s_setprio(1);
#pragma unroll
    for (int i = 4; i < 8; ++i)
#pragma unroll
      for (int j = 0; j < 4; ++j)
        acc[i][j] = __builtin_amdgcn_mfma_f32_16x16x32_f16(af[i], bf[j],
                                                           acc[i][j], 0, 0, 0);
    __builtin_amdgcn_s_setprio(0);
    // caller: [vmcnt] + exit barrier
  };

  // prologue: pieces 0,1,2 in flight (12 gloads)
  stageA(0); stageB(0);
  stageA(1); stageB(1);
  stageA(2); stageB(2);
  wait_vmcnt<8>();   // piece 0 landed (newer: pieces 1,2 = 8 loads)
  barrier_fence();

  // 128 pieces = 64 K-tiles x 2 k-halves. End-of-piece vmcnt(8): pieces
  // p+2,p+3 in flight (8 loads), piece p+1 guaranteed landed before the
  // exit barrier (every wave executes the wait pre-barrier).
  for (int p = 0; p < 125; ++p) {
    piece(p, true);
    wait_vmcnt<8>();
    barrier_fence();
  }
  piece(125, false);
  wait_vmcnt<4>();
  barrier_fence();
  piece(126, false);
  wait_vmcnt<0>();
  barrier_fence();
  piece(127, false);

  // epilogue: C/D layout col=lane&15, row=quad*4+reg; fp16-round, store f32
#pragma unroll
  for (int i = 0; i < 8; ++i) {
#pragma unroll
    for (int j = 0; j < 4; ++j) {
      const int col = n_base + nq * 64 + j * 16 + l15;
#pragma unroll
      for (int r = 0; r < 4; ++r) {
        const int row = m_base + mq * 128 + i * 16 + quad * 4 + r;
        C[(size_t)row * NDIM + col] = __half2float(__float2half(acc[i][j][r]));
      }
    }
  }
}

// ---------------- fallback: fused single-kernel (round-3, 331 us) --------
#define STR 72
__global__ __launch_bounds__(NT) void qgemm_fused(
    const float* __restrict__ A, const int* __restrict__ Wq,
    const float* __restrict__ Sc, float* __restrict__ C) {
  __shared__ __align__(16) _Float16 As[128 * STR];
  __shared__ __align__(16) _Float16 Bs[128 * STR];
  const int tid = threadIdx.x;
  const int bx = blockIdx.x & 31, by = blockIdx.x >> 5;
  const int m_base = by * 128, n_base = bx * 128;
  const int wave = tid >> 6, lane = tid & 63;
  const int l15 = lane & 15, quad = lane >> 4;
  const int wm = (wave & 1) * 64, wn = (wave >> 1) * 64;
  const int bn_local = tid & 127, bk_half = (tid >> 7) * 8;
  const int gn = n_base + bn_local;
  f32x4 acc[4][4];
#pragma unroll
  for (int i = 0; i < 4; ++i)
#pragma unroll
    for (int j = 0; j < 4; ++j) acc[i][j] = (f32x4)0.0f;
  for (int kt = 0; kt < KDIM / 64; ++kt) {
    const int k0 = kt * 64;
    __syncthreads();
#pragma unroll
    for (int i = 0; i < 8; ++i) {
      const int c = i * 256 + tid;
      const int row = c >> 4, col4 = (c & 15) * 4;
      const float4 f = *(const float4*)(A + (size_t)(m_base + row) * KDIM + k0 + col4);
      u32 pk[2];
      pk[0] = pkrtz(f.x, f.y);
      pk[1] = pkrtz(f.z, f.w);
      *(uint2*)&As[(size_t)row * STR + col4] = *(const uint2*)pk;
    }
    {
      const __half hs = __float2half(Sc[(size_t)(k0 >> 7) * NDIM + gn]);
      const __half2 s2 = __half2half2(hs);
      const __half2 nb2 = __half2half2(__hmul(hs, __float2half(-1024.0f)));
#pragma unroll
      for (int it = 0; it < 4; ++it) {
        const int k = bk_half + it * 16;
        u32 v[8];
#pragma unroll
        for (int j = 0; j < 8; ++j)
          v[j] = (u32)Wq[(size_t)(k0 + k + j) * NDIM + gn];
        u32 pk[4];
#pragma unroll
        for (int p = 0; p < 4; ++p) {
          u32 u = v[2 * p] | (v[2 * p + 1] << 16) | 0x64006400u;
          pk[p] = as_u32(__hfma2(as_half2(u), s2, nb2));
        }
        *(uint4*)&Bs[(size_t)bn_local * STR + k] = *(const uint4*)pk;
      }
    }
    __syncthreads();
#pragma unroll
    for (int ks = 0; ks < 64; ks += 32) {
      f16x8 af[4], bf[4];
#pragma unroll
      for (int i = 0; i < 4; ++i)
        af[i] = *(const f16x8*)&As[(size_t)(wm + i * 16 + l15) * STR + ks + quad * 8];
#pragma unroll
      for (int j = 0; j < 4; ++j)
        bf[j] = *(const f16x8*)&Bs[(size_t)(wn + j * 16 + l15) * STR + ks + quad * 8];
#pragma unroll
      for (int i = 0; i < 4; ++i)
#pragma unroll
        for (int j = 0; j < 4; ++j)
          acc[i][j] = __builtin_amdgcn_mfma_f32_16x16x32_f16(af[i], bf[j],
                                                             acc[i][j], 0, 0, 0);
    }
  }
#pragma unroll
  for (int i = 0; i < 4; ++i)
#pragma unroll
    for (int j = 0; j < 4; ++j) {
      const int col = n_base + wn + j * 16 + l15;
#pragma unroll
      for (int r = 0; r < 4; ++r) {
        const int row = m_base + wm + i * 16 + quad * 4 + r;
        C[(size_t)row * NDIM + col] = __half2float(__float2half(acc[i][j][r]));
      }
    }
}

extern "C" void kernel_launch(void* const* d_in, const int* in_sizes, int n_in,
                              void* d_out, int out_size, void* d_ws, size_t ws_size,
                              hipStream_t stream) {
  const float* a = (const float*)d_in[0];
  const int* wq = (const int*)d_in[1];
  const float* sc = (const float*)d_in[2];
  float* out = (float*)d_out;

  const size_t a16_bytes = (size_t)MDIM * KDIM * 2;  // 32 MiB
  const size_t wt_bytes = (size_t)NDIM * KDIM * 2;   // 32 MiB

  if (ws_size >= a16_bytes + wt_bytes) {
    _Float16* a16 = (_Float16*)d_ws;
    _Float16* wt = (_Float16*)((char*)d_ws + a16_bytes);
    const int a_blocks = (MDIM * KDIM) / (NT * 8);  // 8192
    prep<<<WBLK + a_blocks, NT, 0, stream>>>(a, a16, wq, sc, wt);
    gemm_f16<<<(MDIM / 256) * (NDIM / 256), 512, 0, stream>>>(a16, wt, out);
  } else {
    qgemm_fused<<<(MDIM / 128) * (NDIM / 128), NT, 0, stream>>>(a, wq, sc, out);
  }
}